// Round 9
// baseline (219.527 us; speedup 1.0000x reference)
//
#include <hip/hip_runtime.h>
#include <hip/hip_bf16.h>

// B=2, N=1024/branch, H=1024, NH=16, d=64, S=2N=2048. I/O f32; compute bf16 MFMA.
#define NB      2
#define NSEQ    1024
#define S2      2048
#define HDIM    1024
#define NHEADS  16
#define DHEAD   64
// Q is pre-scaled by 0.125*log2(e) in the QKV epilogue; attention uses exp2.
#define Q_SCALE 0.18033688011112042f

typedef unsigned short ushort_t;
typedef __attribute__((ext_vector_type(8))) short short8;   // 8 bf16 = 4 VGPR (MFMA A/B frag)
typedef __attribute__((ext_vector_type(4))) float f32x4;    // MFMA C/D frag (16x16)
typedef __attribute__((ext_vector_type(16))) float f32x16;  // MFMA C/D frag (32x32)

__device__ __forceinline__ ushort_t f2bf(float f) {
    union { float f; unsigned int u; } c; c.f = f;
    unsigned int u = c.u;
    u += 0x7FFFu + ((u >> 16) & 1u);   // RTNE
    return (ushort_t)(u >> 16);
}

__device__ __forceinline__ float bf2f(ushort_t u) {
    union { unsigned int u; float f; } c; c.u = ((unsigned int)u) << 16;
    return c.f;
}

__device__ __forceinline__ unsigned pack_bf16x2(float a, float b) {
    union { __hip_bfloat162 h; unsigned u; } cv;
    cv.h = __float22bfloat162_rn(float2{a, b});   // v_cvt_pk_bf16_f32 on gfx950
    return cv.u;
}

// ---------------------------------------------------------------------------
// One-shot f32 -> bf16 convert of x, x2, w_qkv, w_out into workspace.
// ---------------------------------------------------------------------------
__global__ __launch_bounds__(256) void cvt_all(
    const float* __restrict__ x, const float* __restrict__ x2,
    const float* __restrict__ wqkv, const float* __restrict__ wout,
    ushort_t* __restrict__ Xb, ushort_t* __restrict__ Wqb, ushort_t* __restrict__ Wob)
{
    int b = blockIdx.x;
    const float* s; ushort_t* d; int i;
    if (b < 2048)      { s = x;    d = Xb;            i = b * 256 + threadIdx.x; }
    else if (b < 4096) { s = x2;   d = Xb + 2097152;  i = (b - 2048) * 256 + threadIdx.x; }
    else if (b < 7168) { s = wqkv; d = Wqb;           i = (b - 4096) * 256 + threadIdx.x; }
    else               { s = wout; d = Wob;           i = (b - 7168) * 256 + threadIdx.x; }
    float4 v = ((const float4*)s)[i];
    ushort4 o; o.x = f2bf(v.x); o.y = f2bf(v.y); o.z = f2bf(v.z); o.w = f2bf(v.w);
    ((ushort4*)d)[i] = o;
}

// ---------------------------------------------------------------------------
// QKV MFMA GEMM: C[4096,3072] = Xb @ Wqb^T. 128x128 tile, BK=32, async
// global_load_lds DOUBLE-BUFFERED (one barrier per K-iter). REVERTED to the
// R7 form: 2D grid (24,32). NOTE: with gridDim.x=24 (== 0 mod 8), the
// round-robin dispatch gives xcd = linear_id % 8 = blockIdx.x % 8 -> a STABLE
// column->XCD mapping (each XCD keeps a 768KB B-slice L2-resident while
// streaming A). R8's "chunked rectangle" remap broke this and regressed ~8us.
// Epilogue (R7): full 128B-row stores via per-wave LDS transpose (As reused
// as scratch after the final barrier).
// ---------------------------------------------------------------------------
__global__ __launch_bounds__(256) void qkv_gemm_mfma(
    const ushort_t* __restrict__ Xb, const ushort_t* __restrict__ Wqb,
    ushort_t* __restrict__ Qb, ushort_t* __restrict__ Kb, ushort_t* __restrict__ Vtb)
{
    __shared__ ushort_t As[2 * 128 * 32];   // 16 KB (dbuf; reused as epilogue scratch)
    __shared__ ushort_t Bs[2 * 128 * 32];   // 16 KB
    const int t = threadIdx.x;
    const int lane = t & 63, quad = lane >> 4, l15 = lane & 15;
    const int w = t >> 6;
    const int wm = (w >> 1) * 64, wn = (w & 1) * 64;
    const int r0 = blockIdx.y * 128, c0 = blockIdx.x * 128;

    const int g_chunk = (lane & 3) ^ ((lane >> 3) & 3);   // lane-const global chunk
    const int srow_lo = w * 16 + (lane >> 2);             // row for issue p=0 (p adds 64)

    auto stage = [&](int k0, int buf) {
        #pragma unroll
        for (int p = 0; p < 2; ++p) {
            int row = srow_lo + p * 64;
            const ushort_t* gpA = Xb  + (size_t)(r0 + row) * HDIM + k0 + g_chunk * 8;
            const ushort_t* gpB = Wqb + (size_t)(c0 + row) * HDIM + k0 + g_chunk * 8;
            ushort_t* lpA = As + buf * 4096 + p * 2048 + w * 512;
            ushort_t* lpB = Bs + buf * 4096 + p * 2048 + w * 512;
            __builtin_amdgcn_global_load_lds(
                (const __attribute__((address_space(1))) void*)gpA,
                (__attribute__((address_space(3))) void*)lpA, 16, 0, 0);
            __builtin_amdgcn_global_load_lds(
                (const __attribute__((address_space(1))) void*)gpB,
                (__attribute__((address_space(3))) void*)lpB, 16, 0, 0);
        }
    };

    f32x4 acc[4][4];
    #pragma unroll
    for (int i = 0; i < 4; ++i)
        #pragma unroll
        for (int j = 0; j < 4; ++j) acc[i][j] = (f32x4){0.f, 0.f, 0.f, 0.f};

    stage(0, 0);
    stage(32, 1);
    __syncthreads();

    const int sw = (l15 >> 1) & 3;   // (ra>>1)&3 for frag rows
    for (int it = 0; it < 32; ++it) {
        const ushort_t* a = As + (it & 1) * 4096;
        const ushort_t* b = Bs + (it & 1) * 4096;
        short8 af[4], bf[4];
        #pragma unroll
        for (int mi = 0; mi < 4; ++mi) {
            int ra = wm + mi * 16 + l15;
            af[mi] = *(const short8*)(a + ra * 32 + ((quad ^ sw) * 8));
        }
        #pragma unroll
        for (int ni = 0; ni < 4; ++ni) {
            int rb = wn + ni * 16 + l15;
            bf[ni] = *(const short8*)(b + rb * 32 + ((quad ^ sw) * 8));
        }
        #pragma unroll
        for (int mi = 0; mi < 4; ++mi)
            #pragma unroll
            for (int ni = 0; ni < 4; ++ni)
                acc[mi][ni] = __builtin_amdgcn_mfma_f32_16x16x32_bf16(af[mi], bf[ni], acc[mi][ni], 0, 0, 0);
        __syncthreads();   // all waves done with buf (it&1); drain covers prefetch it+1
        if (it < 30) stage((it + 2) * 32, it & 1);
    }
    // After the it=31 __syncthreads all staging traffic is complete:
    // As is free as per-wave epilogue scratch (4 KB/wave; [16][72] tile used).

    const int branch = r0 >> 11;
    const int bb     = (r0 & 2047) >> 10;
    const int qi     = c0 >> 10;            // 0=Q 1=K 2=V
    ushort_t* sq = As + w * 2048;           // per-wave [16][72] ushort tile
    const int erow = lane >> 2, ech = lane & 3;
    const int cc64 = (c0 & 1023) + wn;      // 64-aligned column base of this wave

    if (qi == 2) {
        // V -> [b,h,d,s]: per ni (16-d block), gather across mi -> [16 d][64 s].
        const int sb64 = branch * NSEQ + (r0 & 1023) + wm;
        #pragma unroll
        for (int ni = 0; ni < 4; ++ni) {
            int cc = cc64 + ni * 16;
            int h = cc >> 6, dbase = cc & 63;
            #pragma unroll
            for (int mi = 0; mi < 4; ++mi)
                #pragma unroll
                for (int reg = 0; reg < 4; ++reg)
                    sq[l15 * 72 + mi * 16 + quad * 4 + reg] = f2bf(acc[mi][ni][reg]);
            short8 v0 = *(const short8*)(sq + erow * 72 + ech * 16);
            short8 v1 = *(const short8*)(sq + erow * 72 + ech * 16 + 8);
            ushort_t* dst = Vtb + ((size_t)(bb * NHEADS + h) * DHEAD + dbase + erow) * S2
                                + sb64 + ech * 16;
            *(short8*)dst = v0;
            *(short8*)(dst + 8) = v1;
        }
    } else {
        // Q/K -> [b,h,s,d]: per mi (16-s block), gather across ni -> [16 s][64 d].
        const float qsc = (qi == 0) ? Q_SCALE : 1.0f;
        ushort_t* base = (qi ? Kb : Qb);
        const int h = cc64 >> 6;            // 64-wide span lies in one head
        #pragma unroll
        for (int mi = 0; mi < 4; ++mi) {
            int sb = branch * NSEQ + (r0 & 1023) + wm + mi * 16;
            #pragma unroll
            for (int ni = 0; ni < 4; ++ni)
                #pragma unroll
                for (int reg = 0; reg < 4; ++reg)
                    sq[(quad * 4 + reg) * 72 + ni * 16 + l15] = f2bf(acc[mi][ni][reg] * qsc);
            short8 v0 = *(const short8*)(sq + erow * 72 + ech * 16);
            short8 v1 = *(const short8*)(sq + erow * 72 + ech * 16 + 8);
            ushort_t* dst = base + ((size_t)(bb * NHEADS + h) * S2 + sb + erow) * DHEAD
                                 + ech * 16;
            *(short8*)dst = v0;
            *(short8*)(dst + 8) = v1;
        }
    }
}

// ---------------------------------------------------------------------------
// MFMA flash attention v10 per (b,h). (unchanged from R6/R7/R8)
// Key-split x2, grid 1024, __launch_bounds__(256,4): 64 arch VGPR + 64 AGPR,
// no spill, Occupancy ~29%. Swapped-operand 32x32x16 QK^T, in-register
// softmax (cvt_pk + permlane32), NO-MAX softmax. Partial O/l out; proj
// now fuses the (O0+O1)/(l0+l1) combine into its A-staging.
// ---------------------------------------------------------------------------
__global__ __launch_bounds__(256, 4) void attn_mfma(
    const ushort_t* __restrict__ Qb, const ushort_t* __restrict__ Kb,
    const ushort_t* __restrict__ Vtb, ushort_t* __restrict__ Op0,
    ushort_t* __restrict__ Op1, float* __restrict__ Lp)
{
    __shared__ ushort_t Ks[2 * 64 * 64];   // 16 KB (dbuf)
    __shared__ ushort_t Vs[2 * 64 * 64];   // 16 KB

    const int t = threadIdx.x, lane = t & 63, w = t >> 6;
    const int l31 = lane & 31, hi = lane >> 5;

    const int id   = blockIdx.x;                 // 0..1023
    const int j    = id >> 3;                    // 0..127
    const int bh   = ((j & 3) << 3) | (id & 7);  // 0..31
    const int j2   = j >> 2;                     // 0..31
    const int r0   = (j2 & 15) << 7;             // q-tile base
    const int half = j2 >> 4;                    // key half
    const int kts  = half * 16;                  // first kt tile

    const ushort_t* Qh  = Qb  + (size_t)bh * S2 * DHEAD;
    const ushort_t* Kh  = Kb  + (size_t)bh * S2 * DHEAD;
    const ushort_t* Vth = Vtb + (size_t)bh * DHEAD * S2;

    const int slot = lane & 7;
    const int rsub = lane >> 3;
    auto prefetch = [&](int kt_, int buf_) {
        #pragma unroll
        for (int c = 0; c < 2; ++c) {
            int row = w * 16 + c * 8 + rsub;
            int g   = slot ^ (row & 7);          // same swizzle for K (over key) and V (over d)
            const ushort_t* gpK = Kh  + (size_t)(kt_ * 64 + row) * DHEAD + g * 8;
            const ushort_t* gpV = Vth + (size_t)row * S2 + kt_ * 64 + g * 8;
            ushort_t* lpK = &Ks[buf_ * 4096 + w * 1024 + c * 512];
            ushort_t* lpV = &Vs[buf_ * 4096 + w * 1024 + c * 512];
            __builtin_amdgcn_global_load_lds(
                (const __attribute__((address_space(1))) void*)gpK,
                (__attribute__((address_space(3))) void*)lpK, 16, 0, 0);
            __builtin_amdgcn_global_load_lds(
                (const __attribute__((address_space(1))) void*)gpV,
                (__attribute__((address_space(3))) void*)lpV, 16, 0, 0);
        }
    };

    // Q fragments (B operand): aq[sd] = Q[q = r0+32w+l31][d = sd*16 + hi*8 .. +7]
    short8 aq[4];
    {
        const ushort_t* qp = Qh + (size_t)(r0 + 32 * w + l31) * DHEAD + hi * 8;
        #pragma unroll
        for (int sd = 0; sd < 4; ++sd) aq[sd] = *(const short8*)(qp + sd * 16);
    }

    // Loop-invariant swizzled LDS byte offsets. For both K (row=key, chunk over d)
    // and V (row=d, chunk over key): off = row*128B + ((s*2+hi)^(row&7))*16B.
    const int s7 = l31 & 7;
    int offA[4];
    #pragma unroll
    for (int s = 0; s < 4; ++s)
        offA[s] = (l31 * 64 + (((s * 2 + hi) ^ s7) * 8)) * 2;

    f32x16 oacc0, oacc1;
    #pragma unroll
    for (int i = 0; i < 16; ++i) { oacc0[i] = 0.f; oacc1[i] = 0.f; }
    float la0 = 0.f, la1 = 0.f, la2 = 0.f, la3 = 0.f;

    // Prologue: stage both buffers (8 loads outstanding).
    prefetch(kts, 0);
    prefetch(kts + 1, 1);

    #pragma unroll 1
    for (int i = 0; i < 16; ++i) {
        // Top sync: tile i resident across all waves.
        if (i < 15) asm volatile("s_waitcnt vmcnt(4)" ::: "memory");
        else        asm volatile("s_waitcnt vmcnt(0)" ::: "memory");
        __builtin_amdgcn_s_barrier();
        __builtin_amdgcn_sched_barrier(0);

        const char* kb = (const char*)Ks + (i & 1) * 8192;
        const char* vb = (const char*)Vs + (i & 1) * 8192;

        // QK(i): swapped-operand 32x32x16; s0 = S^T[keys 0..31][q], s1 = keys 32..63.
        f32x16 s0, s1;
        #pragma unroll
        for (int z = 0; z < 16; ++z) { s0[z] = 0.f; s1[z] = 0.f; }
        __builtin_amdgcn_s_setprio(1);
        #pragma unroll
        for (int sd = 0; sd < 4; ++sd) {
            short8 k0 = *(const short8*)(kb + offA[sd]);
            short8 k1 = *(const short8*)(kb + offA[sd] + 4096);
            s0 = __builtin_amdgcn_mfma_f32_32x32x16_bf16(k0, aq[sd], s0, 0, 0, 0);
            s1 = __builtin_amdgcn_mfma_f32_32x32x16_bf16(k1, aq[sd], s1, 0, 0, 0);
        }
        __builtin_amdgcn_s_setprio(0);

        // SM(i): in-register softmax + P^T redistribution.
        unsigned pw[4][4];   // pw[sk][word]: A-frag words for key-step sk (16 keys)
        #pragma unroll
        for (int halfp = 0; halfp < 2; ++halfp) {
            float p[8], q[8];
            #pragma unroll
            for (int jj = 0; jj < 8; ++jj) {
                p[jj] = __builtin_exp2f(s0[halfp * 8 + jj]);
                q[jj] = __builtin_exp2f(s1[halfp * 8 + jj]);
            }
            la0 += p[0] + p[4]; la1 += p[1] + p[5];
            la2 += p[2] + p[6]; la3 += p[3] + p[7];
            la0 += q[0] + q[4]; la1 += q[1] + q[5];
            la2 += q[2] + q[6]; la3 += q[3] + q[7];

            unsigned a0 = pack_bf16x2(p[0], p[1]), b0 = pack_bf16x2(p[2], p[3]);
            unsigned c0_ = pack_bf16x2(p[4], p[5]), d0_ = pack_bf16x2(p[6], p[7]);
            asm("v_permlane32_swap_b32 %0, %1" : "+v"(a0), "+v"(c0_));
            asm("v_permlane32_swap_b32 %0, %1" : "+v"(b0), "+v"(d0_));
            pw[halfp][0] = a0; pw[halfp][1] = b0; pw[halfp][2] = c0_; pw[halfp][3] = d0_;

            unsigned a1 = pack_bf16x2(q[0], q[1]), b1 = pack_bf16x2(q[2], q[3]);
            unsigned c1_ = pack_bf16x2(q[4], q[5]), d1_ = pack_bf16x2(q[6], q[7]);
            asm("v_permlane32_swap_b32 %0, %1" : "+v"(a1), "+v"(c1_));
            asm("v_permlane32_swap_b32 %0, %1" : "+v"(b1), "+v"(d1_));
            pw[2 + halfp][0] = a1; pw[2 + halfp][1] = b1; pw[2 + halfp][2] = c1_; pw[2 + halfp][3] = d1_;
        }

        // PV(i): O[q][d] += P[q][keys] V[keys][d], two d-tiles of 32.
        __builtin_amdgcn_s_setprio(1);
        #pragma unroll
        for (int sk = 0; sk < 4; ++sk) {
            union { unsigned u[4]; short8 s8; } pa;
            pa.u[0] = pw[sk][0]; pa.u[1] = pw[sk][1];
            pa.u[2] = pw[sk][2]; pa.u[3] = pw[sk][3];
            short8 v0 = *(const short8*)(vb + offA[sk]);
            short8 v1 = *(const short8*)(vb + offA[sk] + 4096);
            oacc0 = __builtin_amdgcn_mfma_f32_32x32x16_bf16(pa.s8, v0, oacc0, 0, 0, 0);
            oacc1 = __builtin_amdgcn_mfma_f32_32x32x16_bf16(pa.s8, v1, oacc1, 0, 0, 0);
        }
        __builtin_amdgcn_s_setprio(0);

        // Tail: rewrite buf (i&1) only after all waves finished reading tile i.
        if (i <= 13) {
            __builtin_amdgcn_s_barrier();
            prefetch(kts + i + 2, i & 1);
        }
    }

    // Partial l for q=l31 (both 32-halves summed); lanes 0-31 store.
    float l = (la0 + la1) + (la2 + la3);
    l += __shfl_xor(l, 32);
    const size_t rowb = (size_t)bh * S2 + r0 + 32 * w;
    if (hi == 0) Lp[(size_t)half * (32 * S2) + rowb + l31] = l;

    // Partial O (UNNORMALIZED) in bf16.
    ushort_t* obase = (half ? Op1 : Op0) + rowb * DHEAD;
    #pragma unroll
    for (int r = 0; r < 16; ++r) {
        const int ql = (r & 3) + 8 * (r >> 2) + 4 * hi;   // q row of oacc reg r
        const size_t rowoff = (size_t)ql * DHEAD;
        obase[rowoff + l31]      = f2bf(oacc0[r]);
        obase[rowoff + 32 + l31] = f2bf(oacc1[r]);
    }
}

// ---------------------------------------------------------------------------
// Proj MFMA GEMM with FUSED COMBINE (R9): out[4096,1024] (f32) =
// [inv(bh,s)*(O0+O1)] @ Wob^T + b_out, where inv = 1/(l0+l1).
// inv depends on h (a K index!), so it is applied during A-STAGING, not the
// epilogue. A is reg-staged (T14 split): per-lane loads of Op0/Op1/Lp issued
// at the TOP of the iteration (hidden under MFMA), normalize+pack+ds_write
// AFTER the barrier (same hazard scheme as the gload_lds version: buf it&1
// rewritten only post-barrier; visibility via next __syncthreads).
// B staging stays global_load_lds. Replaces the combine_o kernel entirely
// (saves one launch + 24.5 MB HBM round-trip). 2D grid (16,32): gridDim.x=16
// (== 0 mod 8) keeps the accidental stable column->XCD L2 mapping.
// ---------------------------------------------------------------------------
__global__ __launch_bounds__(256) void proj_gemm_mfma(
    const ushort_t* __restrict__ Op0, const ushort_t* __restrict__ Op1,
    const float* __restrict__ Lp, const ushort_t* __restrict__ Wob,
    const float* __restrict__ Bo, float* __restrict__ Out)
{
    __shared__ ushort_t As[2 * 128 * 32];   // 16 KB
    __shared__ ushort_t Bs[2 * 64 * 32];    // 8 KB
    __shared__ float    Sc[4][16 * 20];
    const int t = threadIdx.x;
    const int lane = t & 63, quad = lane >> 4, l15 = lane & 15;
    const int w = t >> 6;
    const int wm = (w >> 1) * 64, wn = (w & 1) * 32;
    const int r0 = blockIdx.y * 128, c0 = blockIdx.x * 64;
    const int branch = r0 >> 11, bb = (r0 & 2047) >> 10;

    const int g_chunk = (lane & 3) ^ ((lane >> 3) & 3);
    const int srow_lo = w * 16 + (lane >> 2);

    // A-load (issue early): per k-tile k0, two row-segments p=0,1.
    short8 pa0[2], pa1[2];
    float  pl[2];
    auto aload = [&](int k0) {
        int h = k0 >> 6, off = k0 & 63;
        #pragma unroll
        for (int p = 0; p < 2; ++p) {
            int row = srow_lo + p * 64;
            size_t bhS = (size_t)(bb * NHEADS + h) * S2 + branch * NSEQ + (r0 & 1023) + row;
            const ushort_t* src0 = Op0 + bhS * DHEAD + off + g_chunk * 8;
            const ushort_t* src1 = Op1 + bhS * DHEAD + off + g_chunk * 8;
            pa0[p] = *(const short8*)src0;
            pa1[p] = *(const short8*)src1;
            pl[p]  = Lp[bhS] + Lp[32 * S2 + bhS];
        }
    };
    // A-write (late): normalize, pack bf16, stage to LDS at gload_lds layout
    // (wave-uniform base + lane*16B).
    auto awrite = [&](int buf) {
        #pragma unroll
        for (int p = 0; p < 2; ++p) {
            float inv = 1.0f / pl[p];
            union { short8 v; ushort_t u[8]; } x0, x1;
            x0.v = pa0[p]; x1.v = pa1[p];
            union { unsigned uw[4]; short8 v; } o;
            #pragma unroll
            for (int q2 = 0; q2 < 4; ++q2)
                o.uw[q2] = pack_bf16x2((bf2f(x0.u[2 * q2])     + bf2f(x1.u[2 * q2]))     * inv,
                                       (bf2f(x0.u[2 * q2 + 1]) + bf2f(x1.u[2 * q2 + 1])) * inv);
            *(short8*)(As + buf * 4096 + p * 2048 + w * 512 + lane * 8) = o.v;
        }
    };
    auto stageB = [&](int k0, int buf) {
        const ushort_t* gpB = Wob + (size_t)(c0 + srow_lo) * HDIM + k0 + g_chunk * 8;
        ushort_t* lpB = Bs + buf * 2048 + w * 512;
        __builtin_amdgcn_global_load_lds(
            (const __attribute__((address_space(1))) void*)gpB,
            (__attribute__((address_space(3))) void*)lpB, 16, 0, 0);
    };

    f32x4 acc[4][2];
    #pragma unroll
    for (int i = 0; i < 4; ++i)
        #pragma unroll
        for (int j = 0; j < 2; ++j) acc[i][j] = (f32x4){0.f, 0.f, 0.f, 0.f};

    // Prologue: synchronously stage tiles 0 and 1.
    aload(0);  stageB(0, 0);  awrite(0);
    aload(32); stageB(32, 1); awrite(1);
    __syncthreads();

    const int sw = (l15 >> 1) & 3;
    for (int it = 0; it < 32; ++it) {
        if (it < 30) aload((it + 2) * 32);   // issue early; consumed after barrier

        const ushort_t* a = As + (it & 1) * 4096;
        const ushort_t* b = Bs + (it & 1) * 2048;
        short8 af[4], bf[2];
        #pragma unroll
        for (int mi = 0; mi < 4; ++mi) {
            int ra = wm + mi * 16 + l15;
            af[mi] = *(const short8*)(a + ra * 32 + ((quad ^ sw) * 8));
        }
        #pragma unroll
        for (int ni = 0; ni < 2; ++ni) {
            int rb = wn + ni * 16 + l15;
            bf[ni] = *(const short8*)(b + rb * 32 + ((quad ^ sw) * 8));
        }
        #pragma unroll
        for (int mi = 0; mi < 4; ++mi)
            #pragma unroll
            for (int ni = 0; ni < 2; ++ni)
                acc[mi][ni] = __builtin_amdgcn_mfma_f32_16x16x32_bf16(af[mi], bf[ni], acc[mi][ni], 0, 0, 0);
        __syncthreads();   // all waves done reading buf (it&1); drains vm+lgkm
        if (it < 30) {
            awrite(it & 1);            // vmcnt wait covered by the MFMA phase
            stageB((it + 2) * 32, it & 1);
        }
    }

    float* sc = &Sc[w][0];
    const int row = lane >> 2, ch = lane & 3;
    #pragma unroll
    for (int mi = 0; mi < 4; ++mi) {
        int rb0 = r0 + wm + mi * 16;
        #pragma unroll
        for (int ni = 0; ni < 2; ++ni) {
            int cb = c0 + wn + ni * 16;
            #pragma unroll
            for (int reg = 0; reg < 4; ++reg)
                sc[(quad * 4 + reg) * 20 + l15] = acc[mi][ni][reg];
            float4 v = *(const float4*)&sc[row * 20 + ch * 4];
            float4 bias = *(const float4*)&Bo[cb + ch * 4];
            v.x += bias.x; v.y += bias.y; v.z += bias.z; v.w += bias.w;
            *(float4*)&Out[(size_t)(rb0 + row) * HDIM + cb + ch * 4] = v;
        }
    }
}

extern "C" void kernel_launch(void* const* d_in, const int* in_sizes, int n_in,
                              void* d_out, int out_size, void* d_ws, size_t ws_size,
                              hipStream_t stream) {
    const float* x    = (const float*)d_in[0];
    const float* x2   = (const float*)d_in[1];
    const float* wqkv = (const float*)d_in[2];
    const float* wout = (const float*)d_in[3];
    const float* bout = (const float*)d_in[4];
    float* out = (float*)d_out;

    // ws layout (48 MB), time-multiplexed:
    //  [ 0, 8): Xb (cvt->qkv)   -> Op0 (attn -> proj A)
    //  [ 8,14): Wqb (cvt->qkv)  -> Lp (attn l-partials, 512 KB)
    //  [14,16): Wob (cvt->proj)
    //  [16,24): Qb  | [24,32): Kb | [32,40): Vtb   (qkv->attn)
    //  [40,48): Op1 (attn->proj)
    char* ws = (char*)d_ws;
    ushort_t* Xb  = (ushort_t*)(ws);
    ushort_t* Wqb = (ushort_t*)(ws + (8u  << 20));
    ushort_t* Wob = (ushort_t*)(ws + (14u << 20));
    ushort_t* Qb  = (ushort_t*)(ws + (16u << 20));
    ushort_t* Kb  = (ushort_t*)(ws + (24u << 20));
    ushort_t* Vtb = (ushort_t*)(ws + (32u << 20));
    ushort_t* Op0 = (ushort_t*)(ws);
    float*    Lp  = (float*)   (ws + (8u  << 20));
    ushort_t* Op1 = (ushort_t*)(ws + (40u << 20));

    cvt_all<<<8192, 256, 0, stream>>>(x, x2, wqkv, wout, Xb, Wqb, Wob);
    qkv_gemm_mfma<<<dim3(24, 32), 256, 0, stream>>>(Xb, Wqb, Qb, Kb, Vtb);
    attn_mfma<<<1024, 256, 0, stream>>>(Qb, Kb, Vtb, Op0, Op1, Lp);
    proj_gemm_mfma<<<dim3(16, 32), 256, 0, stream>>>(Op0, Op1, Lp, Wob, bout, out);
}

// Round 10
// 202.285 us; speedup vs baseline: 1.0852x; 1.0852x over previous
//
#include <hip/hip_runtime.h>
#include <hip/hip_bf16.h>

// B=2, N=1024/branch, H=1024, NH=16, d=64, S=2N=2048. I/O f32; compute bf16 MFMA.
#define NB      2
#define NSEQ    1024
#define S2      2048
#define HDIM    1024
#define NHEADS  16
#define DHEAD   64
// Q is pre-scaled by 0.125*log2(e) in the QKV epilogue; attention uses exp2.
#define Q_SCALE 0.18033688011112042f

typedef unsigned short ushort_t;
typedef __attribute__((ext_vector_type(8))) short short8;   // 8 bf16 = 4 VGPR (MFMA A/B frag)
typedef __attribute__((ext_vector_type(4))) float f32x4;    // MFMA C/D frag (16x16)
typedef __attribute__((ext_vector_type(16))) float f32x16;  // MFMA C/D frag (32x32)

__device__ __forceinline__ ushort_t f2bf(float f) {
    union { float f; unsigned int u; } c; c.f = f;
    unsigned int u = c.u;
    u += 0x7FFFu + ((u >> 16) & 1u);   // RTNE
    return (ushort_t)(u >> 16);
}

__device__ __forceinline__ float bf2f(ushort_t u) {
    union { unsigned int u; float f; } c; c.u = ((unsigned int)u) << 16;
    return c.f;
}

__device__ __forceinline__ unsigned pack_bf16x2(float a, float b) {
    union { __hip_bfloat162 h; unsigned u; } cv;
    cv.h = __float22bfloat162_rn(float2{a, b});   // v_cvt_pk_bf16_f32 on gfx950
    return cv.u;
}

// ---------------------------------------------------------------------------
// One-shot f32 -> bf16 convert of x, x2, w_qkv, w_out into workspace.
// ---------------------------------------------------------------------------
__global__ __launch_bounds__(256) void cvt_all(
    const float* __restrict__ x, const float* __restrict__ x2,
    const float* __restrict__ wqkv, const float* __restrict__ wout,
    ushort_t* __restrict__ Xb, ushort_t* __restrict__ Wqb, ushort_t* __restrict__ Wob)
{
    int b = blockIdx.x;
    const float* s; ushort_t* d; int i;
    if (b < 2048)      { s = x;    d = Xb;            i = b * 256 + threadIdx.x; }
    else if (b < 4096) { s = x2;   d = Xb + 2097152;  i = (b - 2048) * 256 + threadIdx.x; }
    else if (b < 7168) { s = wqkv; d = Wqb;           i = (b - 4096) * 256 + threadIdx.x; }
    else               { s = wout; d = Wob;           i = (b - 7168) * 256 + threadIdx.x; }
    float4 v = ((const float4*)s)[i];
    ushort4 o; o.x = f2bf(v.x); o.y = f2bf(v.y); o.z = f2bf(v.z); o.w = f2bf(v.w);
    ((ushort4*)d)[i] = o;
}

// ---------------------------------------------------------------------------
// QKV MFMA GEMM: C[4096,3072] = Xb @ Wqb^T. 128x128 tile, BK=32, async
// global_load_lds DOUBLE-BUFFERED (one barrier per K-iter). R10 = R7 form:
// 2D grid (24,32). gridDim.x=24 (== 0 mod 8) -> round-robin dispatch gives
// xcd = blockIdx.x % 8, a STABLE column->XCD mapping (each XCD keeps a 768KB
// B-slice L2-resident while streaming A). R8's remap broke this; reverted.
// R10 adds __launch_bounds__(256,3): reg cap 170 >> ~140 live (acc 64 AGPR +
// frags 32 + addr) -> no spill possible; guarantees >=3 waves/SIMD.
// Epilogue (R7): full 128B-row stores via per-wave LDS transpose (As reused
// as scratch after the final barrier).
// ---------------------------------------------------------------------------
__global__ __launch_bounds__(256, 3) void qkv_gemm_mfma(
    const ushort_t* __restrict__ Xb, const ushort_t* __restrict__ Wqb,
    ushort_t* __restrict__ Qb, ushort_t* __restrict__ Kb, ushort_t* __restrict__ Vtb)
{
    __shared__ ushort_t As[2 * 128 * 32];   // 16 KB (dbuf; reused as epilogue scratch)
    __shared__ ushort_t Bs[2 * 128 * 32];   // 16 KB
    const int t = threadIdx.x;
    const int lane = t & 63, quad = lane >> 4, l15 = lane & 15;
    const int w = t >> 6;
    const int wm = (w >> 1) * 64, wn = (w & 1) * 64;
    const int r0 = blockIdx.y * 128, c0 = blockIdx.x * 128;

    const int g_chunk = (lane & 3) ^ ((lane >> 3) & 3);   // lane-const global chunk
    const int srow_lo = w * 16 + (lane >> 2);             // row for issue p=0 (p adds 64)

    auto stage = [&](int k0, int buf) {
        #pragma unroll
        for (int p = 0; p < 2; ++p) {
            int row = srow_lo + p * 64;
            const ushort_t* gpA = Xb  + (size_t)(r0 + row) * HDIM + k0 + g_chunk * 8;
            const ushort_t* gpB = Wqb + (size_t)(c0 + row) * HDIM + k0 + g_chunk * 8;
            ushort_t* lpA = As + buf * 4096 + p * 2048 + w * 512;
            ushort_t* lpB = Bs + buf * 4096 + p * 2048 + w * 512;
            __builtin_amdgcn_global_load_lds(
                (const __attribute__((address_space(1))) void*)gpA,
                (__attribute__((address_space(3))) void*)lpA, 16, 0, 0);
            __builtin_amdgcn_global_load_lds(
                (const __attribute__((address_space(1))) void*)gpB,
                (__attribute__((address_space(3))) void*)lpB, 16, 0, 0);
        }
    };

    f32x4 acc[4][4];
    #pragma unroll
    for (int i = 0; i < 4; ++i)
        #pragma unroll
        for (int j = 0; j < 4; ++j) acc[i][j] = (f32x4){0.f, 0.f, 0.f, 0.f};

    stage(0, 0);
    stage(32, 1);
    __syncthreads();

    const int sw = (l15 >> 1) & 3;   // (ra>>1)&3 for frag rows
    for (int it = 0; it < 32; ++it) {
        const ushort_t* a = As + (it & 1) * 4096;
        const ushort_t* b = Bs + (it & 1) * 4096;
        short8 af[4], bf[4];
        #pragma unroll
        for (int mi = 0; mi < 4; ++mi) {
            int ra = wm + mi * 16 + l15;
            af[mi] = *(const short8*)(a + ra * 32 + ((quad ^ sw) * 8));
        }
        #pragma unroll
        for (int ni = 0; ni < 4; ++ni) {
            int rb = wn + ni * 16 + l15;
            bf[ni] = *(const short8*)(b + rb * 32 + ((quad ^ sw) * 8));
        }
        #pragma unroll
        for (int mi = 0; mi < 4; ++mi)
            #pragma unroll
            for (int ni = 0; ni < 4; ++ni)
                acc[mi][ni] = __builtin_amdgcn_mfma_f32_16x16x32_bf16(af[mi], bf[ni], acc[mi][ni], 0, 0, 0);
        __syncthreads();   // all waves done with buf (it&1); drain covers prefetch it+1
        if (it < 30) stage((it + 2) * 32, it & 1);
    }
    // After the it=31 __syncthreads all staging traffic is complete:
    // As is free as per-wave epilogue scratch (4 KB/wave; [16][72] tile used).

    const int branch = r0 >> 11;
    const int bb     = (r0 & 2047) >> 10;
    const int qi     = c0 >> 10;            // 0=Q 1=K 2=V
    ushort_t* sq = As + w * 2048;           // per-wave [16][72] ushort tile
    const int erow = lane >> 2, ech = lane & 3;
    const int cc64 = (c0 & 1023) + wn;      // 64-aligned column base of this wave

    if (qi == 2) {
        // V -> [b,h,d,s]: per ni (16-d block), gather across mi -> [16 d][64 s].
        const int sb64 = branch * NSEQ + (r0 & 1023) + wm;
        #pragma unroll
        for (int ni = 0; ni < 4; ++ni) {
            int cc = cc64 + ni * 16;
            int h = cc >> 6, dbase = cc & 63;
            #pragma unroll
            for (int mi = 0; mi < 4; ++mi)
                #pragma unroll
                for (int reg = 0; reg < 4; ++reg)
                    sq[l15 * 72 + mi * 16 + quad * 4 + reg] = f2bf(acc[mi][ni][reg]);
            short8 v0 = *(const short8*)(sq + erow * 72 + ech * 16);
            short8 v1 = *(const short8*)(sq + erow * 72 + ech * 16 + 8);
            ushort_t* dst = Vtb + ((size_t)(bb * NHEADS + h) * DHEAD + dbase + erow) * S2
                                + sb64 + ech * 16;
            *(short8*)dst = v0;
            *(short8*)(dst + 8) = v1;
        }
    } else {
        // Q/K -> [b,h,s,d]: per mi (16-s block), gather across ni -> [16 s][64 d].
        const float qsc = (qi == 0) ? Q_SCALE : 1.0f;
        ushort_t* base = (qi ? Kb : Qb);
        const int h = cc64 >> 6;            // 64-wide span lies in one head
        #pragma unroll
        for (int mi = 0; mi < 4; ++mi) {
            int sb = branch * NSEQ + (r0 & 1023) + wm + mi * 16;
            #pragma unroll
            for (int ni = 0; ni < 4; ++ni)
                #pragma unroll
                for (int reg = 0; reg < 4; ++reg)
                    sq[(quad * 4 + reg) * 72 + ni * 16 + l15] = f2bf(acc[mi][ni][reg] * qsc);
            short8 v0 = *(const short8*)(sq + erow * 72 + ech * 16);
            short8 v1 = *(const short8*)(sq + erow * 72 + ech * 16 + 8);
            ushort_t* dst = base + ((size_t)(bb * NHEADS + h) * S2 + sb + erow) * DHEAD
                                 + ech * 16;
            *(short8*)dst = v0;
            *(short8*)(dst + 8) = v1;
        }
    }
}

// ---------------------------------------------------------------------------
// MFMA flash attention v10 per (b,h). (unchanged since R6; 66us, Occ ~29%)
// Key-split x2, grid 1024, __launch_bounds__(256,4): 64 arch VGPR + 64 AGPR,
// no spill. Swapped-operand 32x32x16 QK^T, in-register softmax (cvt_pk +
// permlane32), NO-MAX softmax. Partial O (bf16) + l (f32) out + combine.
// ---------------------------------------------------------------------------
__global__ __launch_bounds__(256, 4) void attn_mfma(
    const ushort_t* __restrict__ Qb, const ushort_t* __restrict__ Kb,
    const ushort_t* __restrict__ Vtb, ushort_t* __restrict__ Op0,
    ushort_t* __restrict__ Op1, float* __restrict__ Lp)
{
    __shared__ ushort_t Ks[2 * 64 * 64];   // 16 KB (dbuf)
    __shared__ ushort_t Vs[2 * 64 * 64];   // 16 KB

    const int t = threadIdx.x, lane = t & 63, w = t >> 6;
    const int l31 = lane & 31, hi = lane >> 5;

    const int id   = blockIdx.x;                 // 0..1023
    const int j    = id >> 3;                    // 0..127
    const int bh   = ((j & 3) << 3) | (id & 7);  // 0..31
    const int j2   = j >> 2;                     // 0..31
    const int r0   = (j2 & 15) << 7;             // q-tile base
    const int half = j2 >> 4;                    // key half
    const int kts  = half * 16;                  // first kt tile

    const ushort_t* Qh  = Qb  + (size_t)bh * S2 * DHEAD;
    const ushort_t* Kh  = Kb  + (size_t)bh * S2 * DHEAD;
    const ushort_t* Vth = Vtb + (size_t)bh * DHEAD * S2;

    const int slot = lane & 7;
    const int rsub = lane >> 3;
    auto prefetch = [&](int kt_, int buf_) {
        #pragma unroll
        for (int c = 0; c < 2; ++c) {
            int row = w * 16 + c * 8 + rsub;
            int g   = slot ^ (row & 7);          // same swizzle for K (over key) and V (over d)
            const ushort_t* gpK = Kh  + (size_t)(kt_ * 64 + row) * DHEAD + g * 8;
            const ushort_t* gpV = Vth + (size_t)row * S2 + kt_ * 64 + g * 8;
            ushort_t* lpK = &Ks[buf_ * 4096 + w * 1024 + c * 512];
            ushort_t* lpV = &Vs[buf_ * 4096 + w * 1024 + c * 512];
            __builtin_amdgcn_global_load_lds(
                (const __attribute__((address_space(1))) void*)gpK,
                (__attribute__((address_space(3))) void*)lpK, 16, 0, 0);
            __builtin_amdgcn_global_load_lds(
                (const __attribute__((address_space(1))) void*)gpV,
                (__attribute__((address_space(3))) void*)lpV, 16, 0, 0);
        }
    };

    // Q fragments (B operand): aq[sd] = Q[q = r0+32w+l31][d = sd*16 + hi*8 .. +7]
    short8 aq[4];
    {
        const ushort_t* qp = Qh + (size_t)(r0 + 32 * w + l31) * DHEAD + hi * 8;
        #pragma unroll
        for (int sd = 0; sd < 4; ++sd) aq[sd] = *(const short8*)(qp + sd * 16);
    }

    // Loop-invariant swizzled LDS byte offsets. For both K (row=key, chunk over d)
    // and V (row=d, chunk over key): off = row*128B + ((s*2+hi)^(row&7))*16B.
    const int s7 = l31 & 7;
    int offA[4];
    #pragma unroll
    for (int s = 0; s < 4; ++s)
        offA[s] = (l31 * 64 + (((s * 2 + hi) ^ s7) * 8)) * 2;

    f32x16 oacc0, oacc1;
    #pragma unroll
    for (int i = 0; i < 16; ++i) { oacc0[i] = 0.f; oacc1[i] = 0.f; }
    float la0 = 0.f, la1 = 0.f, la2 = 0.f, la3 = 0.f;

    // Prologue: stage both buffers (8 loads outstanding).
    prefetch(kts, 0);
    prefetch(kts + 1, 1);

    #pragma unroll 1
    for (int i = 0; i < 16; ++i) {
        // Top sync: tile i resident across all waves.
        if (i < 15) asm volatile("s_waitcnt vmcnt(4)" ::: "memory");
        else        asm volatile("s_waitcnt vmcnt(0)" ::: "memory");
        __builtin_amdgcn_s_barrier();
        __builtin_amdgcn_sched_barrier(0);

        const char* kb = (const char*)Ks + (i & 1) * 8192;
        const char* vb = (const char*)Vs + (i & 1) * 8192;

        // QK(i): swapped-operand 32x32x16; s0 = S^T[keys 0..31][q], s1 = keys 32..63.
        f32x16 s0, s1;
        #pragma unroll
        for (int z = 0; z < 16; ++z) { s0[z] = 0.f; s1[z] = 0.f; }
        __builtin_amdgcn_s_setprio(1);
        #pragma unroll
        for (int sd = 0; sd < 4; ++sd) {
            short8 k0 = *(const short8*)(kb + offA[sd]);
            short8 k1 = *(const short8*)(kb + offA[sd] + 4096);
            s0 = __builtin_amdgcn_mfma_f32_32x32x16_bf16(k0, aq[sd], s0, 0, 0, 0);
            s1 = __builtin_amdgcn_mfma_f32_32x32x16_bf16(k1, aq[sd], s1, 0, 0, 0);
        }
        __builtin_amdgcn_s_setprio(0);

        // SM(i): in-register softmax + P^T redistribution.
        unsigned pw[4][4];   // pw[sk][word]: A-frag words for key-step sk (16 keys)
        #pragma unroll
        for (int halfp = 0; halfp < 2; ++halfp) {
            float p[8], q[8];
            #pragma unroll
            for (int jj = 0; jj < 8; ++jj) {
                p[jj] = __builtin_exp2f(s0[halfp * 8 + jj]);
                q[jj] = __builtin_exp2f(s1[halfp * 8 + jj]);
            }
            la0 += p[0] + p[4]; la1 += p[1] + p[5];
            la2 += p[2] + p[6]; la3 += p[3] + p[7];
            la0 += q[0] + q[4]; la1 += q[1] + q[5];
            la2 += q[2] + q[6]; la3 += q[3] + q[7];

            unsigned a0 = pack_bf16x2(p[0], p[1]), b0 = pack_bf16x2(p[2], p[3]);
            unsigned c0_ = pack_bf16x2(p[4], p[5]), d0_ = pack_bf16x2(p[6], p[7]);
            asm("v_permlane32_swap_b32 %0, %1" : "+v"(a0), "+v"(c0_));
            asm("v_permlane32_swap_b32 %0, %1" : "+v"(b0), "+v"(d0_));
            pw[halfp][0] = a0; pw[halfp][1] = b0; pw[halfp][2] = c0_; pw[halfp][3] = d0_;

            unsigned a1 = pack_bf16x2(q[0], q[1]), b1 = pack_bf16x2(q[2], q[3]);
            unsigned c1_ = pack_bf16x2(q[4], q[5]), d1_ = pack_bf16x2(q[6], q[7]);
            asm("v_permlane32_swap_b32 %0, %1" : "+v"(a1), "+v"(c1_));
            asm("v_permlane32_swap_b32 %0, %1" : "+v"(b1), "+v"(d1_));
            pw[2 + halfp][0] = a1; pw[2 + halfp][1] = b1; pw[2 + halfp][2] = c1_; pw[2 + halfp][3] = d1_;
        }

        // PV(i): O[q][d] += P[q][keys] V[keys][d], two d-tiles of 32.
        __builtin_amdgcn_s_setprio(1);
        #pragma unroll
        for (int sk = 0; sk < 4; ++sk) {
            union { unsigned u[4]; short8 s8; } pa;
            pa.u[0] = pw[sk][0]; pa.u[1] = pw[sk][1];
            pa.u[2] = pw[sk][2]; pa.u[3] = pw[sk][3];
            short8 v0 = *(const short8*)(vb + offA[sk]);
            short8 v1 = *(const short8*)(vb + offA[sk] + 4096);
            oacc0 = __builtin_amdgcn_mfma_f32_32x32x16_bf16(pa.s8, v0, oacc0, 0, 0, 0);
            oacc1 = __builtin_amdgcn_mfma_f32_32x32x16_bf16(pa.s8, v1, oacc1, 0, 0, 0);
        }
        __builtin_amdgcn_s_setprio(0);

        // Tail: rewrite buf (i&1) only after all waves finished reading tile i.
        if (i <= 13) {
            __builtin_amdgcn_s_barrier();
            prefetch(kts + i + 2, i & 1);
        }
    }

    // Partial l for q=l31 (both 32-halves summed); lanes 0-31 store.
    float l = (la0 + la1) + (la2 + la3);
    l += __shfl_xor(l, 32);
    const size_t rowb = (size_t)bh * S2 + r0 + 32 * w;
    if (hi == 0) Lp[(size_t)half * (32 * S2) + rowb + l31] = l;

    // Partial O (UNNORMALIZED) in bf16.
    ushort_t* obase = (half ? Op1 : Op0) + rowb * DHEAD;
    #pragma unroll
    for (int r = 0; r < 16; ++r) {
        const int ql = (r & 3) + 8 * (r >> 2) + 4 * hi;   // q row of oacc reg r
        const size_t rowoff = (size_t)ql * DHEAD;
        obase[rowoff + l31]      = f2bf(oacc0[r]);
        obase[rowoff + 32 + l31] = f2bf(oacc1[r]);
    }
}

// ---------------------------------------------------------------------------
// Combine: O = (O0 + O1) / (l0 + l1), elementwise, in-place into Op0 (which
// becomes Ob, the proj input). Done ONCE here (8MB write) -- R9 proved that
// fusing this into proj multiplies it by proj's 16x A-panel re-read.
// ---------------------------------------------------------------------------
__global__ __launch_bounds__(256) void combine_o(
    const ushort_t* __restrict__ Op1, const float* __restrict__ Lp,
    ushort_t* __restrict__ Ob /* == Op0, in-place */)
{
    int idx = blockIdx.x * 256 + threadIdx.x;   // 524288 threads
    int e   = idx * 8;
    int row = e >> 6;
    float inv = 1.0f / (Lp[row] + Lp[32 * S2 + row]);
    union { short8 v; ushort_t u[8]; } a, b, o;
    a.v = *(const short8*)(Ob + e);
    b.v = *(const short8*)(Op1 + e);
    #pragma unroll
    for (int jj = 0; jj < 8; ++jj)
        o.u[jj] = f2bf((bf2f(a.u[jj]) + bf2f(b.u[jj])) * inv);
    *(short8*)(Ob + e) = o.v;
}

// ---------------------------------------------------------------------------
// Proj MFMA GEMM: out[4096,1024] (f32) = gather(O)[4096,1024] @ Wob^T + b_out.
// BM=128 x BN=64, 2D grid (16,32): gridDim.x=16 (== 0 mod 8) keeps the stable
// column->XCD L2 mapping. Async staging double-buffered (one barrier/K-iter).
// R10 adds __launch_bounds__(256,4): cap 128 >> ~100 live (acc 32 AGPR) ->
// no spill; guarantees 4 waves/SIMD. Epilogue: LDS transpose -> f32x4 stores.
// ---------------------------------------------------------------------------
__global__ __launch_bounds__(256, 4) void proj_gemm_mfma(
    const ushort_t* __restrict__ Ob, const ushort_t* __restrict__ Wob,
    const float* __restrict__ Bo, float* __restrict__ Out)
{
    __shared__ ushort_t As[2 * 128 * 32];   // 16 KB
    __shared__ ushort_t Bs[2 * 64 * 32];    // 8 KB
    __shared__ float    Sc[4][16 * 20];
    const int t = threadIdx.x;
    const int lane = t & 63, quad = lane >> 4, l15 = lane & 15;
    const int w = t >> 6;
    const int wm = (w >> 1) * 64, wn = (w & 1) * 32;
    const int r0 = blockIdx.y * 128, c0 = blockIdx.x * 64;
    const int branch = r0 >> 11, bb = (r0 & 2047) >> 10;

    const int g_chunk = (lane & 3) ^ ((lane >> 3) & 3);
    const int srow_lo = w * 16 + (lane >> 2);

    auto stage = [&](int k0, int buf) {
        int h = k0 >> 6, off = k0 & 63;
        const ushort_t* gpB = Wob + (size_t)(c0 + srow_lo) * HDIM + k0 + g_chunk * 8;
        ushort_t* lpB = Bs + buf * 2048 + w * 512;
        __builtin_amdgcn_global_load_lds(
            (const __attribute__((address_space(1))) void*)gpB,
            (__attribute__((address_space(3))) void*)lpB, 16, 0, 0);
        #pragma unroll
        for (int p = 0; p < 2; ++p) {
            int row = srow_lo + p * 64;
            int s = branch * NSEQ + (r0 & 1023) + row;
            const ushort_t* gpA = Ob + ((size_t)(bb * NHEADS + h) * S2 + s) * DHEAD + off + g_chunk * 8;
            ushort_t* lpA = As + buf * 4096 + p * 2048 + w * 512;
            __builtin_amdgcn_global_load_lds(
                (const __attribute__((address_space(1))) void*)gpA,
                (__attribute__((address_space(3))) void*)lpA, 16, 0, 0);
        }
    };

    f32x4 acc[4][2];
    #pragma unroll
    for (int i = 0; i < 4; ++i)
        #pragma unroll
        for (int j = 0; j < 2; ++j) acc[i][j] = (f32x4){0.f, 0.f, 0.f, 0.f};

    stage(0, 0);
    stage(32, 1);
    __syncthreads();

    const int sw = (l15 >> 1) & 3;
    for (int it = 0; it < 32; ++it) {
        const ushort_t* a = As + (it & 1) * 4096;
        const ushort_t* b = Bs + (it & 1) * 2048;
        short8 af[4], bf[2];
        #pragma unroll
        for (int mi = 0; mi < 4; ++mi) {
            int ra = wm + mi * 16 + l15;
            af[mi] = *(const short8*)(a + ra * 32 + ((quad ^ sw) * 8));
        }
        #pragma unroll
        for (int ni = 0; ni < 2; ++ni) {
            int rb = wn + ni * 16 + l15;
            bf[ni] = *(const short8*)(b + rb * 32 + ((quad ^ sw) * 8));
        }
        #pragma unroll
        for (int mi = 0; mi < 4; ++mi)
            #pragma unroll
            for (int ni = 0; ni < 2; ++ni)
                acc[mi][ni] = __builtin_amdgcn_mfma_f32_16x16x32_bf16(af[mi], bf[ni], acc[mi][ni], 0, 0, 0);
        __syncthreads();
        if (it < 30) stage((it + 2) * 32, it & 1);
    }

    float* sc = &Sc[w][0];
    const int row = lane >> 2, ch = lane & 3;
    #pragma unroll
    for (int mi = 0; mi < 4; ++mi) {
        int rb0 = r0 + wm + mi * 16;
        #pragma unroll
        for (int ni = 0; ni < 2; ++ni) {
            int cb = c0 + wn + ni * 16;
            #pragma unroll
            for (int reg = 0; reg < 4; ++reg)
                sc[(quad * 4 + reg) * 20 + l15] = acc[mi][ni][reg];
            float4 v = *(const float4*)&sc[row * 20 + ch * 4];
            float4 bias = *(const float4*)&Bo[cb + ch * 4];
            v.x += bias.x; v.y += bias.y; v.z += bias.z; v.w += bias.w;
            *(float4*)&Out[(size_t)(rb0 + row) * HDIM + cb + ch * 4] = v;
        }
    }
}

extern "C" void kernel_launch(void* const* d_in, const int* in_sizes, int n_in,
                              void* d_out, int out_size, void* d_ws, size_t ws_size,
                              hipStream_t stream) {
    const float* x    = (const float*)d_in[0];
    const float* x2   = (const float*)d_in[1];
    const float* wqkv = (const float*)d_in[2];
    const float* wout = (const float*)d_in[3];
    const float* bout = (const float*)d_in[4];
    float* out = (float*)d_out;

    // ws layout (48 MB), time-multiplexed:
    //  [ 0, 8): Xb (cvt->qkv)   -> Op0 (attn) -> Ob (combine in-place, proj A)
    //  [ 8,14): Wqb (cvt->qkv)  -> Lp (attn l-partials, 512 KB)
    //  [14,16): Wob (cvt->proj)
    //  [16,24): Qb  | [24,32): Kb | [32,40): Vtb   (qkv->attn)
    //  [40,48): Op1 (attn->combine)
    char* ws = (char*)d_ws;
    ushort_t* Xb  = (ushort_t*)(ws);
    ushort_t* Wqb = (ushort_t*)(ws + (8u  << 20));
    ushort_t* Wob = (ushort_t*)(ws + (14u << 20));
    ushort_t* Qb  = (ushort_t*)(ws + (16u << 20));
    ushort_t* Kb  = (ushort_t*)(ws + (24u << 20));
    ushort_t* Vtb = (ushort_t*)(ws + (32u << 20));
    ushort_t* Op0 = (ushort_t*)(ws);
    float*    Lp  = (float*)   (ws + (8u  << 20));
    ushort_t* Op1 = (ushort_t*)(ws + (40u << 20));

    cvt_all<<<8192, 256, 0, stream>>>(x, x2, wqkv, wout, Xb, Wqb, Wob);
    qkv_gemm_mfma<<<dim3(24, 32), 256, 0, stream>>>(Xb, Wqb, Qb, Kb, Vtb);
    attn_mfma<<<1024, 256, 0, stream>>>(Qb, Kb, Vtb, Op0, Op1, Lp);
    combine_o<<<2048, 256, 0, stream>>>(Op1, Lp, Op0);
    proj_gemm_mfma<<<dim3(16, 32), 256, 0, stream>>>(Op0, Wob, bout, out);
}

// Round 11
// 201.483 us; speedup vs baseline: 1.0896x; 1.0040x over previous
//
#include <hip/hip_runtime.h>
#include <hip/hip_bf16.h>

// B=2, N=1024/branch, H=1024, NH=16, d=64, S=2N=2048. I/O f32; compute bf16 MFMA.
#define NB      2
#define NSEQ    1024
#define S2      2048
#define HDIM    1024
#define NHEADS  16
#define DHEAD   64
// Q is pre-scaled by 0.125*log2(e) in the QKV epilogue; attention uses exp2.
#define Q_SCALE 0.18033688011112042f

typedef unsigned short ushort_t;
typedef __attribute__((ext_vector_type(8))) short short8;   // 8 bf16 = 4 VGPR (MFMA A/B frag)
typedef __attribute__((ext_vector_type(4))) float f32x4;    // MFMA C/D frag (16x16)
typedef __attribute__((ext_vector_type(16))) float f32x16;  // MFMA C/D frag (32x32)

__device__ __forceinline__ ushort_t f2bf(float f) {
    union { float f; unsigned int u; } c; c.f = f;
    unsigned int u = c.u;
    u += 0x7FFFu + ((u >> 16) & 1u);   // RTNE
    return (ushort_t)(u >> 16);
}

__device__ __forceinline__ float bf2f(ushort_t u) {
    union { unsigned int u; float f; } c; c.u = ((unsigned int)u) << 16;
    return c.f;
}

__device__ __forceinline__ unsigned pack_bf16x2(float a, float b) {
    union { __hip_bfloat162 h; unsigned u; } cv;
    cv.h = __float22bfloat162_rn(float2{a, b});   // v_cvt_pk_bf16_f32 on gfx950
    return cv.u;
}

// ---------------------------------------------------------------------------
// One-shot f32 -> bf16 convert of x, x2, w_qkv, w_out into workspace.
// ---------------------------------------------------------------------------
__global__ __launch_bounds__(256) void cvt_all(
    const float* __restrict__ x, const float* __restrict__ x2,
    const float* __restrict__ wqkv, const float* __restrict__ wout,
    ushort_t* __restrict__ Xb, ushort_t* __restrict__ Wqb, ushort_t* __restrict__ Wob)
{
    int b = blockIdx.x;
    const float* s; ushort_t* d; int i;
    if (b < 2048)      { s = x;    d = Xb;            i = b * 256 + threadIdx.x; }
    else if (b < 4096) { s = x2;   d = Xb + 2097152;  i = (b - 2048) * 256 + threadIdx.x; }
    else if (b < 7168) { s = wqkv; d = Wqb;           i = (b - 4096) * 256 + threadIdx.x; }
    else               { s = wout; d = Wob;           i = (b - 7168) * 256 + threadIdx.x; }
    float4 v = ((const float4*)s)[i];
    ushort4 o; o.x = f2bf(v.x); o.y = f2bf(v.y); o.z = f2bf(v.z); o.w = f2bf(v.w);
    ((ushort4*)d)[i] = o;
}

// ---------------------------------------------------------------------------
// QKV MFMA GEMM: C[4096,3072] = Xb @ Wqb^T. 128x128 tile, BK=32, async
// global_load_lds. 2D grid (24,32): gridDim.x=24 (== 0 mod 8) -> round-robin
// dispatch gives xcd = blockIdx.x % 8, a STABLE column->XCD mapping (each XCD
// keeps a 768KB B-slice L2-resident while streaming A).
// R11: TRIPLE-buffered staging, ONE barrier per K-iter with counted vmcnt(4)
// (stage(i+1) stays in flight across the barrier; never drains to 0 mid-loop).
// Race-freedom: stage(i+2) -> buf (i+2)%3 is issued after compute(i); any
// wave there has passed barrier(i), reached only after ALL waves finished
// compute(i-1) = the last readers of that buffer. (Same proof as attn's R6
// loop.) LDS 48 KB - free, grid-limited to 3 blocks/CU.
// Epilogue (R7): full 128B-row stores via per-wave LDS transpose; explicit
// __syncthreads before reusing As as scratch (buf1 overlaps scratch region).
// ---------------------------------------------------------------------------
__global__ __launch_bounds__(256, 3) void qkv_gemm_mfma(
    const ushort_t* __restrict__ Xb, const ushort_t* __restrict__ Wqb,
    ushort_t* __restrict__ Qb, ushort_t* __restrict__ Kb, ushort_t* __restrict__ Vtb)
{
    __shared__ ushort_t As[3 * 128 * 32];   // 24 KB (3-buf; reused as epilogue scratch)
    __shared__ ushort_t Bs[3 * 128 * 32];   // 24 KB
    const int t = threadIdx.x;
    const int lane = t & 63, quad = lane >> 4, l15 = lane & 15;
    const int w = t >> 6;
    const int wm = (w >> 1) * 64, wn = (w & 1) * 64;
    const int r0 = blockIdx.y * 128, c0 = blockIdx.x * 128;

    const int g_chunk = (lane & 3) ^ ((lane >> 3) & 3);   // lane-const global chunk
    const int srow_lo = w * 16 + (lane >> 2);             // row for issue p=0 (p adds 64)

    auto stage = [&](int k0, int buf) {    // 4 loads/wave/stage
        #pragma unroll
        for (int p = 0; p < 2; ++p) {
            int row = srow_lo + p * 64;
            const ushort_t* gpA = Xb  + (size_t)(r0 + row) * HDIM + k0 + g_chunk * 8;
            const ushort_t* gpB = Wqb + (size_t)(c0 + row) * HDIM + k0 + g_chunk * 8;
            ushort_t* lpA = As + buf * 4096 + p * 2048 + w * 512;
            ushort_t* lpB = Bs + buf * 4096 + p * 2048 + w * 512;
            __builtin_amdgcn_global_load_lds(
                (const __attribute__((address_space(1))) void*)gpA,
                (__attribute__((address_space(3))) void*)lpA, 16, 0, 0);
            __builtin_amdgcn_global_load_lds(
                (const __attribute__((address_space(1))) void*)gpB,
                (__attribute__((address_space(3))) void*)lpB, 16, 0, 0);
        }
    };

    f32x4 acc[4][4];
    #pragma unroll
    for (int i = 0; i < 4; ++i)
        #pragma unroll
        for (int j = 0; j < 4; ++j) acc[i][j] = (f32x4){0.f, 0.f, 0.f, 0.f};

    stage(0, 0);
    stage(32, 1);

    const int sw = (l15 >> 1) & 3;   // (ra>>1)&3 for frag rows
    int bi = 0;                      // buffer holding tile it
    #pragma unroll 1
    for (int it = 0; it < 32; ++it) {
        // Wait only tile it's 4 loads (stage it+1 stays in flight), then the
        // single per-iter barrier makes all waves' DMA writes visible.
        if (it < 31) asm volatile("s_waitcnt vmcnt(4)" ::: "memory");
        else         asm volatile("s_waitcnt vmcnt(0)" ::: "memory");
        __builtin_amdgcn_s_barrier();
        __builtin_amdgcn_sched_barrier(0);

        const ushort_t* a = As + bi * 4096;
        const ushort_t* b = Bs + bi * 4096;
        short8 af[4], bf[4];
        #pragma unroll
        for (int mi = 0; mi < 4; ++mi) {
            int ra = wm + mi * 16 + l15;
            af[mi] = *(const short8*)(a + ra * 32 + ((quad ^ sw) * 8));
        }
        #pragma unroll
        for (int ni = 0; ni < 4; ++ni) {
            int rb = wn + ni * 16 + l15;
            bf[ni] = *(const short8*)(b + rb * 32 + ((quad ^ sw) * 8));
        }
        #pragma unroll
        for (int mi = 0; mi < 4; ++mi)
            #pragma unroll
            for (int ni = 0; ni < 4; ++ni)
                acc[mi][ni] = __builtin_amdgcn_mfma_f32_16x16x32_bf16(af[mi], bf[ni], acc[mi][ni], 0, 0, 0);

        // Distance-2 prefetch into the third buffer (no tail barrier needed).
        if (it <= 29) {
            int pb = bi + 2; if (pb >= 3) pb -= 3;
            stage((it + 2) * 32, pb);
        }
        bi = (bi == 2) ? 0 : bi + 1;
    }
    __syncthreads();   // all MFMA reads done; As is now free epilogue scratch

    const int branch = r0 >> 11;
    const int bb     = (r0 & 2047) >> 10;
    const int qi     = c0 >> 10;            // 0=Q 1=K 2=V
    ushort_t* sq = As + w * 2048;           // per-wave [16][72] ushort tile
    const int erow = lane >> 2, ech = lane & 3;
    const int cc64 = (c0 & 1023) + wn;      // 64-aligned column base of this wave

    if (qi == 2) {
        // V -> [b,h,d,s]: per ni (16-d block), gather across mi -> [16 d][64 s].
        const int sb64 = branch * NSEQ + (r0 & 1023) + wm;
        #pragma unroll
        for (int ni = 0; ni < 4; ++ni) {
            int cc = cc64 + ni * 16;
            int h = cc >> 6, dbase = cc & 63;
            #pragma unroll
            for (int mi = 0; mi < 4; ++mi)
                #pragma unroll
                for (int reg = 0; reg < 4; ++reg)
                    sq[l15 * 72 + mi * 16 + quad * 4 + reg] = f2bf(acc[mi][ni][reg]);
            short8 v0 = *(const short8*)(sq + erow * 72 + ech * 16);
            short8 v1 = *(const short8*)(sq + erow * 72 + ech * 16 + 8);
            ushort_t* dst = Vtb + ((size_t)(bb * NHEADS + h) * DHEAD + dbase + erow) * S2
                                + sb64 + ech * 16;
            *(short8*)dst = v0;
            *(short8*)(dst + 8) = v1;
        }
    } else {
        // Q/K -> [b,h,s,d]: per mi (16-s block), gather across ni -> [16 s][64 d].
        const float qsc = (qi == 0) ? Q_SCALE : 1.0f;
        ushort_t* base = (qi ? Kb : Qb);
        const int h = cc64 >> 6;            // 64-wide span lies in one head
        #pragma unroll
        for (int mi = 0; mi < 4; ++mi) {
            int sb = branch * NSEQ + (r0 & 1023) + wm + mi * 16;
            #pragma unroll
            for (int ni = 0; ni < 4; ++ni)
                #pragma unroll
                for (int reg = 0; reg < 4; ++reg)
                    sq[(quad * 4 + reg) * 72 + ni * 16 + l15] = f2bf(acc[mi][ni][reg] * qsc);
            short8 v0 = *(const short8*)(sq + erow * 72 + ech * 16);
            short8 v1 = *(const short8*)(sq + erow * 72 + ech * 16 + 8);
            ushort_t* dst = base + ((size_t)(bb * NHEADS + h) * S2 + sb + erow) * DHEAD
                                 + ech * 16;
            *(short8*)dst = v0;
            *(short8*)(dst + 8) = v1;
        }
    }
}

// ---------------------------------------------------------------------------
// MFMA flash attention v10 per (b,h). (unchanged since R6; 66.5us, Occ ~29%)
// Key-split x2, grid 1024, __launch_bounds__(256,4): 64 arch VGPR + 64 AGPR,
// no spill. Swapped-operand 32x32x16 QK^T, in-register softmax (cvt_pk +
// permlane32), NO-MAX softmax. Partial O (bf16) + l (f32) out + combine.
// ---------------------------------------------------------------------------
__global__ __launch_bounds__(256, 4) void attn_mfma(
    const ushort_t* __restrict__ Qb, const ushort_t* __restrict__ Kb,
    const ushort_t* __restrict__ Vtb, ushort_t* __restrict__ Op0,
    ushort_t* __restrict__ Op1, float* __restrict__ Lp)
{
    __shared__ ushort_t Ks[2 * 64 * 64];   // 16 KB (dbuf)
    __shared__ ushort_t Vs[2 * 64 * 64];   // 16 KB

    const int t = threadIdx.x, lane = t & 63, w = t >> 6;
    const int l31 = lane & 31, hi = lane >> 5;

    const int id   = blockIdx.x;                 // 0..1023
    const int j    = id >> 3;                    // 0..127
    const int bh   = ((j & 3) << 3) | (id & 7);  // 0..31
    const int j2   = j >> 2;                     // 0..31
    const int r0   = (j2 & 15) << 7;             // q-tile base
    const int half = j2 >> 4;                    // key half
    const int kts  = half * 16;                  // first kt tile

    const ushort_t* Qh  = Qb  + (size_t)bh * S2 * DHEAD;
    const ushort_t* Kh  = Kb  + (size_t)bh * S2 * DHEAD;
    const ushort_t* Vth = Vtb + (size_t)bh * DHEAD * S2;

    const int slot = lane & 7;
    const int rsub = lane >> 3;
    auto prefetch = [&](int kt_, int buf_) {
        #pragma unroll
        for (int c = 0; c < 2; ++c) {
            int row = w * 16 + c * 8 + rsub;
            int g   = slot ^ (row & 7);          // same swizzle for K (over key) and V (over d)
            const ushort_t* gpK = Kh  + (size_t)(kt_ * 64 + row) * DHEAD + g * 8;
            const ushort_t* gpV = Vth + (size_t)row * S2 + kt_ * 64 + g * 8;
            ushort_t* lpK = &Ks[buf_ * 4096 + w * 1024 + c * 512];
            ushort_t* lpV = &Vs[buf_ * 4096 + w * 1024 + c * 512];
            __builtin_amdgcn_global_load_lds(
                (const __attribute__((address_space(1))) void*)gpK,
                (__attribute__((address_space(3))) void*)lpK, 16, 0, 0);
            __builtin_amdgcn_global_load_lds(
                (const __attribute__((address_space(1))) void*)gpV,
                (__attribute__((address_space(3))) void*)lpV, 16, 0, 0);
        }
    };

    // Q fragments (B operand): aq[sd] = Q[q = r0+32w+l31][d = sd*16 + hi*8 .. +7]
    short8 aq[4];
    {
        const ushort_t* qp = Qh + (size_t)(r0 + 32 * w + l31) * DHEAD + hi * 8;
        #pragma unroll
        for (int sd = 0; sd < 4; ++sd) aq[sd] = *(const short8*)(qp + sd * 16);
    }

    // Loop-invariant swizzled LDS byte offsets. For both K (row=key, chunk over d)
    // and V (row=d, chunk over key): off = row*128B + ((s*2+hi)^(row&7))*16B.
    const int s7 = l31 & 7;
    int offA[4];
    #pragma unroll
    for (int s = 0; s < 4; ++s)
        offA[s] = (l31 * 64 + (((s * 2 + hi) ^ s7) * 8)) * 2;

    f32x16 oacc0, oacc1;
    #pragma unroll
    for (int i = 0; i < 16; ++i) { oacc0[i] = 0.f; oacc1[i] = 0.f; }
    float la0 = 0.f, la1 = 0.f, la2 = 0.f, la3 = 0.f;

    // Prologue: stage both buffers (8 loads outstanding).
    prefetch(kts, 0);
    prefetch(kts + 1, 1);

    #pragma unroll 1
    for (int i = 0; i < 16; ++i) {
        // Top sync: tile i resident across all waves.
        if (i < 15) asm volatile("s_waitcnt vmcnt(4)" ::: "memory");
        else        asm volatile("s_waitcnt vmcnt(0)" ::: "memory");
        __builtin_amdgcn_s_barrier();
        __builtin_amdgcn_sched_barrier(0);

        const char* kb = (const char*)Ks + (i & 1) * 8192;
        const char* vb = (const char*)Vs + (i & 1) * 8192;

        // QK(i): swapped-operand 32x32x16; s0 = S^T[keys 0..31][q], s1 = keys 32..63.
        f32x16 s0, s1;
        #pragma unroll
        for (int z = 0; z < 16; ++z) { s0[z] = 0.f; s1[z] = 0.f; }
        __builtin_amdgcn_s_setprio(1);
        #pragma unroll
        for (int sd = 0; sd < 4; ++sd) {
            short8 k0 = *(const short8*)(kb + offA[sd]);
            short8 k1 = *(const short8*)(kb + offA[sd] + 4096);
            s0 = __builtin_amdgcn_mfma_f32_32x32x16_bf16(k0, aq[sd], s0, 0, 0, 0);
            s1 = __builtin_amdgcn_mfma_f32_32x32x16_bf16(k1, aq[sd], s1, 0, 0, 0);
        }
        __builtin_amdgcn_s_setprio(0);

        // SM(i): in-register softmax + P^T redistribution.
        unsigned pw[4][4];   // pw[sk][word]: A-frag words for key-step sk (16 keys)
        #pragma unroll
        for (int halfp = 0; halfp < 2; ++halfp) {
            float p[8], q[8];
            #pragma unroll
            for (int jj = 0; jj < 8; ++jj) {
                p[jj] = __builtin_exp2f(s0[halfp * 8 + jj]);
                q[jj] = __builtin_exp2f(s1[halfp * 8 + jj]);
            }
            la0 += p[0] + p[4]; la1 += p[1] + p[5];
            la2 += p[2] + p[6]; la3 += p[3] + p[7];
            la0 += q[0] + q[4]; la1 += q[1] + q[5];
            la2 += q[2] + q[6]; la3 += q[3] + q[7];

            unsigned a0 = pack_bf16x2(p[0], p[1]), b0 = pack_bf16x2(p[2], p[3]);
            unsigned c0_ = pack_bf16x2(p[4], p[5]), d0_ = pack_bf16x2(p[6], p[7]);
            asm("v_permlane32_swap_b32 %0, %1" : "+v"(a0), "+v"(c0_));
            asm("v_permlane32_swap_b32 %0, %1" : "+v"(b0), "+v"(d0_));
            pw[halfp][0] = a0; pw[halfp][1] = b0; pw[halfp][2] = c0_; pw[halfp][3] = d0_;

            unsigned a1 = pack_bf16x2(q[0], q[1]), b1 = pack_bf16x2(q[2], q[3]);
            unsigned c1_ = pack_bf16x2(q[4], q[5]), d1_ = pack_bf16x2(q[6], q[7]);
            asm("v_permlane32_swap_b32 %0, %1" : "+v"(a1), "+v"(c1_));
            asm("v_permlane32_swap_b32 %0, %1" : "+v"(b1), "+v"(d1_));
            pw[2 + halfp][0] = a1; pw[2 + halfp][1] = b1; pw[2 + halfp][2] = c1_; pw[2 + halfp][3] = d1_;
        }

        // PV(i): O[q][d] += P[q][keys] V[keys][d], two d-tiles of 32.
        __builtin_amdgcn_s_setprio(1);
        #pragma unroll
        for (int sk = 0; sk < 4; ++sk) {
            union { unsigned u[4]; short8 s8; } pa;
            pa.u[0] = pw[sk][0]; pa.u[1] = pw[sk][1];
            pa.u[2] = pw[sk][2]; pa.u[3] = pw[sk][3];
            short8 v0 = *(const short8*)(vb + offA[sk]);
            short8 v1 = *(const short8*)(vb + offA[sk] + 4096);
            oacc0 = __builtin_amdgcn_mfma_f32_32x32x16_bf16(pa.s8, v0, oacc0, 0, 0, 0);
            oacc1 = __builtin_amdgcn_mfma_f32_32x32x16_bf16(pa.s8, v1, oacc1, 0, 0, 0);
        }
        __builtin_amdgcn_s_setprio(0);

        // Tail: rewrite buf (i&1) only after all waves finished reading tile i.
        if (i <= 13) {
            __builtin_amdgcn_s_barrier();
            prefetch(kts + i + 2, i & 1);
        }
    }

    // Partial l for q=l31 (both 32-halves summed); lanes 0-31 store.
    float l = (la0 + la1) + (la2 + la3);
    l += __shfl_xor(l, 32);
    const size_t rowb = (size_t)bh * S2 + r0 + 32 * w;
    if (hi == 0) Lp[(size_t)half * (32 * S2) + rowb + l31] = l;

    // Partial O (UNNORMALIZED) in bf16.
    ushort_t* obase = (half ? Op1 : Op0) + rowb * DHEAD;
    #pragma unroll
    for (int r = 0; r < 16; ++r) {
        const int ql = (r & 3) + 8 * (r >> 2) + 4 * hi;   // q row of oacc reg r
        const size_t rowoff = (size_t)ql * DHEAD;
        obase[rowoff + l31]      = f2bf(oacc0[r]);
        obase[rowoff + 32 + l31] = f2bf(oacc1[r]);
    }
}

// ---------------------------------------------------------------------------
// Combine: O = (O0 + O1) / (l0 + l1), elementwise, in-place into Op0 (which
// becomes Ob, the proj input). Done ONCE here (8MB write) -- R9 proved that
// fusing this into proj multiplies it by proj's 16x A-panel re-read.
// ---------------------------------------------------------------------------
__global__ __launch_bounds__(256) void combine_o(
    const ushort_t* __restrict__ Op1, const float* __restrict__ Lp,
    ushort_t* __restrict__ Ob /* == Op0, in-place */)
{
    int idx = blockIdx.x * 256 + threadIdx.x;   // 524288 threads
    int e   = idx * 8;
    int row = e >> 6;
    float inv = 1.0f / (Lp[row] + Lp[32 * S2 + row]);
    union { short8 v; ushort_t u[8]; } a, b, o;
    a.v = *(const short8*)(Ob + e);
    b.v = *(const short8*)(Op1 + e);
    #pragma unroll
    for (int jj = 0; jj < 8; ++jj)
        o.u[jj] = f2bf((bf2f(a.u[jj]) + bf2f(b.u[jj])) * inv);
    *(short8*)(Ob + e) = o.v;
}

// ---------------------------------------------------------------------------
// Proj MFMA GEMM: out[4096,1024] (f32) = gather(O)[4096,1024] @ Wob^T + b_out.
// BM=128 x BN=64, 2D grid (16,32): gridDim.x=16 (== 0 mod 8) keeps the stable
// column->XCD L2 mapping. R11: TRIPLE-buffered staging, ONE barrier per
// K-iter, counted vmcnt(3) (3 loads/wave/stage). Same race-freedom proof as
// qkv. LDS 41 KB - free, grid-limited to 2 blocks/CU. Epilogue: per-wave Sc
// scratch (no cross-wave LDS dependency) -> no trailing barrier needed.
// ---------------------------------------------------------------------------
__global__ __launch_bounds__(256, 4) void proj_gemm_mfma(
    const ushort_t* __restrict__ Ob, const ushort_t* __restrict__ Wob,
    const float* __restrict__ Bo, float* __restrict__ Out)
{
    __shared__ ushort_t As[3 * 128 * 32];   // 24 KB
    __shared__ ushort_t Bs[3 * 64 * 32];    // 12 KB
    __shared__ float    Sc[4][16 * 20];
    const int t = threadIdx.x;
    const int lane = t & 63, quad = lane >> 4, l15 = lane & 15;
    const int w = t >> 6;
    const int wm = (w >> 1) * 64, wn = (w & 1) * 32;
    const int r0 = blockIdx.y * 128, c0 = blockIdx.x * 64;
    const int branch = r0 >> 11, bb = (r0 & 2047) >> 10;

    const int g_chunk = (lane & 3) ^ ((lane >> 3) & 3);
    const int srow_lo = w * 16 + (lane >> 2);

    auto stage = [&](int k0, int buf) {    // 3 loads/wave/stage
        int h = k0 >> 6, off = k0 & 63;
        const ushort_t* gpB = Wob + (size_t)(c0 + srow_lo) * HDIM + k0 + g_chunk * 8;
        ushort_t* lpB = Bs + buf * 2048 + w * 512;
        __builtin_amdgcn_global_load_lds(
            (const __attribute__((address_space(1))) void*)gpB,
            (__attribute__((address_space(3))) void*)lpB, 16, 0, 0);
        #pragma unroll
        for (int p = 0; p < 2; ++p) {
            int row = srow_lo + p * 64;
            int s = branch * NSEQ + (r0 & 1023) + row;
            const ushort_t* gpA = Ob + ((size_t)(bb * NHEADS + h) * S2 + s) * DHEAD + off + g_chunk * 8;
            ushort_t* lpA = As + buf * 4096 + p * 2048 + w * 512;
            __builtin_amdgcn_global_load_lds(
                (const __attribute__((address_space(1))) void*)gpA,
                (__attribute__((address_space(3))) void*)lpA, 16, 0, 0);
        }
    };

    f32x4 acc[4][2];
    #pragma unroll
    for (int i = 0; i < 4; ++i)
        #pragma unroll
        for (int j = 0; j < 2; ++j) acc[i][j] = (f32x4){0.f, 0.f, 0.f, 0.f};

    stage(0, 0);
    stage(32, 1);

    const int sw = (l15 >> 1) & 3;
    int bi = 0;
    #pragma unroll 1
    for (int it = 0; it < 32; ++it) {
        if (it < 31) asm volatile("s_waitcnt vmcnt(3)" ::: "memory");
        else         asm volatile("s_waitcnt vmcnt(0)" ::: "memory");
        __builtin_amdgcn_s_barrier();
        __builtin_amdgcn_sched_barrier(0);

        const ushort_t* a = As + bi * 4096;
        const ushort_t* b = Bs + bi * 2048;
        short8 af[4], bf[2];
        #pragma unroll
        for (int mi = 0; mi < 4; ++mi) {
            int ra = wm + mi * 16 + l15;
            af[mi] = *(const short8*)(a + ra * 32 + ((quad ^ sw) * 8));
        }
        #pragma unroll
        for (int ni = 0; ni < 2; ++ni) {
            int rb = wn + ni * 16 + l15;
            bf[ni] = *(const short8*)(b + rb * 32 + ((quad ^ sw) * 8));
        }
        #pragma unroll
        for (int mi = 0; mi < 4; ++mi)
            #pragma unroll
            for (int ni = 0; ni < 2; ++ni)
                acc[mi][ni] = __builtin_amdgcn_mfma_f32_16x16x32_bf16(af[mi], bf[ni], acc[mi][ni], 0, 0, 0);

        if (it <= 29) {
            int pb = bi + 2; if (pb >= 3) pb -= 3;
            stage((it + 2) * 32, pb);
        }
        bi = (bi == 2) ? 0 : bi + 1;
    }

    float* sc = &Sc[w][0];
    const int row = lane >> 2, ch = lane & 3;
    #pragma unroll
    for (int mi = 0; mi < 4; ++mi) {
        int rb0 = r0 + wm + mi * 16;
        #pragma unroll
        for (int ni = 0; ni < 2; ++ni) {
            int cb = c0 + wn + ni * 16;
            #pragma unroll
            for (int reg = 0; reg < 4; ++reg)
                sc[(quad * 4 + reg) * 20 + l15] = acc[mi][ni][reg];
            float4 v = *(const float4*)&sc[row * 20 + ch * 4];
            float4 bias = *(const float4*)&Bo[cb + ch * 4];
            v.x += bias.x; v.y += bias.y; v.z += bias.z; v.w += bias.w;
            *(float4*)&Out[(size_t)(rb0 + row) * HDIM + cb + ch * 4] = v;
        }
    }
}

extern "C" void kernel_launch(void* const* d_in, const int* in_sizes, int n_in,
                              void* d_out, int out_size, void* d_ws, size_t ws_size,
                              hipStream_t stream) {
    const float* x    = (const float*)d_in[0];
    const float* x2   = (const float*)d_in[1];
    const float* wqkv = (const float*)d_in[2];
    const float* wout = (const float*)d_in[3];
    const float* bout = (const float*)d_in[4];
    float* out = (float*)d_out;

    // ws layout (48 MB), time-multiplexed:
    //  [ 0, 8): Xb (cvt->qkv)   -> Op0 (attn) -> Ob (combine in-place, proj A)
    //  [ 8,14): Wqb (cvt->qkv)  -> Lp (attn l-partials, 512 KB)
    //  [14,16): Wob (cvt->proj)
    //  [16,24): Qb  | [24,32): Kb | [32,40): Vtb   (qkv->attn)
    //  [40,48): Op1 (attn->combine)
    char* ws = (char*)d_ws;
    ushort_t* Xb  = (ushort_t*)(ws);
    ushort_t* Wqb = (ushort_t*)(ws + (8u  << 20));
    ushort_t* Wob = (ushort_t*)(ws + (14u << 20));
    ushort_t* Qb  = (ushort_t*)(ws + (16u << 20));
    ushort_t* Kb  = (ushort_t*)(ws + (24u << 20));
    ushort_t* Vtb = (ushort_t*)(ws + (32u << 20));
    ushort_t* Op0 = (ushort_t*)(ws);
    float*    Lp  = (float*)   (ws + (8u  << 20));
    ushort_t* Op1 = (ushort_t*)(ws + (40u << 20));

    cvt_all<<<8192, 256, 0, stream>>>(x, x2, wqkv, wout, Xb, Wqb, Wob);
    qkv_gemm_mfma<<<dim3(24, 32), 256, 0, stream>>>(Xb, Wqb, Qb, Kb, Vtb);
    attn_mfma<<<1024, 256, 0, stream>>>(Qb, Kb, Vtb, Op0, Op1, Lp);
    combine_o<<<2048, 256, 0, stream>>>(Op1, Lp, Op0);
    proj_gemm_mfma<<<dim3(16, 32), 256, 0, stream>>>(Op0, Wob, bout, out);
}